// Round 15
// baseline (350.370 us; speedup 1.0000x reference)
//
#include <hip/hip_runtime.h>
#include <stdint.h>

#define B_ 128
#define T_ 1000
#define H_ 512
#define PH 16         // steps per full phase
#define NFULL 62      // full phases; tail phase 62 has 8 steps (62*16+8 = 1000)

typedef float vfloat4 __attribute__((ext_vector_type(4)));
typedef float vfloat2 __attribute__((ext_vector_type(2)));

// DPP-based add of a lane-shifted copy. row_shr:N = 0x110|N, row_bcast:15/31 = 0x142/0x143.
template <int CTRL>
__device__ __forceinline__ float dpp_add(float x) {
    int moved = __builtin_amdgcn_update_dpp(0, __float_as_int(x), CTRL, 0xf, 0xf, true);
    return x + __int_as_float(moved);
}

__device__ __forceinline__ void wave_reduce2(float& p0, float& p1) {
    p0 = dpp_add<0x111>(p0); p1 = dpp_add<0x111>(p1);
    p0 = dpp_add<0x112>(p0); p1 = dpp_add<0x112>(p1);
    p0 = dpp_add<0x114>(p0); p1 = dpp_add<0x114>(p1);
    p0 = dpp_add<0x118>(p0); p1 = dpp_add<0x118>(p1);
    p0 = dpp_add<0x142>(p0); p1 = dpp_add<0x142>(p1);
    p0 = dpp_add<0x143>(p0); p1 = dpp_add<0x143>(p1);
}

__device__ __forceinline__ float wave_reduce1(float p) {
    p = dpp_add<0x111>(p); p = dpp_add<0x112>(p); p = dpp_add<0x114>(p);
    p = dpp_add<0x118>(p); p = dpp_add<0x142>(p); p = dpp_add<0x143>(p);
    return p;
}

// tanh(x) = 1 - 2/(e^{2x}+1) via hardware exp2 + rcp.
__device__ __forceinline__ float fast_tanh(float x) {
    float E = __builtin_amdgcn_exp2f(x * 2.885390081777927f);
    float r = __builtin_amdgcn_rcpf(E + 1.0f);
    return __builtin_fmaf(-2.0f, r, 1.0f);
}

#define C2_ 2.885390081777927f   // 2*log2(e)

__device__ __forceinline__ vfloat2 bc2(float x) { vfloat2 v = {x, x}; return v; }

__global__ __launch_bounds__(128, 1) void lowrank_rnn_kernel(
    const float* __restrict__ input,   // (B,T,3)
    const float* __restrict__ noise,   // (B,T,H)
    const float* __restrict__ wi,      // (3,H)
    const float* __restrict__ si,      // (3,)
    const float* __restrict__ m,       // (H,2)
    const float* __restrict__ n,       // (H,2)
    const float* __restrict__ wo,      // (H,1)
    const float* __restrict__ so,      // (1,)
    const float* __restrict__ h0,      // (H,)
    float* __restrict__ out)           // [output (B,T,1) | traj (B,T+1,H)]
{
    const int b    = blockIdx.x;   // one batch element per block (2 waves)
    const int tid  = threadIdx.x;
    const int wid  = tid >> 6;     // 0 = consumer (serial chain), 1 = producer
    const int lane = tid & 63;
    const int j0   = lane * 8;     // hidden units j0..j0+7 owned by this lane

    // Rings: [half][row-in-phase][plane][lane] — 16B/lane stride, conflict-free.
    __shared__ __align__(16) vfloat4 ub[2][PH][2][64];   // 64 KB: u = 0.05z + x·wS
    __shared__ __align__(16) vfloat4 hb[2][PH][2][64];   // 64 KB: h_t
    __shared__ __align__(16) vfloat4 hfin[2][64];        //  2 KB: final h_T
    __shared__ float os[T_ + 1];                         //  4 KB
    __shared__ int   flags[2];                           // [0]=vprod, [1]=vcons

    if (tid == 0) { flags[0] = 0; flags[1] = 0; }
    __syncthreads();   // only full barrier in the kernel
    volatile int* vprod = &flags[0];
    volatile int* vcons = &flags[1];

    if (wid == 1) {
        // ========== PRODUCER: z loads, u precompute, os via exact tanh, traj stores ==========
        float wS0[8], wS1[8], wS2[8], wof[8];
        {
            const float so0 = so[0];
            #pragma unroll
            for (int i = 0; i < 3; ++i) {
                float s = 0.2f * si[i];
                float* dst = (i == 0) ? wS0 : (i == 1) ? wS1 : wS2;
                #pragma unroll
                for (int q = 0; q < 2; ++q) {
                    vfloat4 vw = *(const vfloat4*)(wi + i * H_ + j0 + 4 * q);
                    dst[4*q] = vw.x * s; dst[4*q+1] = vw.y * s;
                    dst[4*q+2] = vw.z * s; dst[4*q+3] = vw.w * s;
                }
            }
            #pragma unroll
            for (int q = 0; q < 2; ++q) {
                vfloat4 vw = *(const vfloat4*)(wo + j0 + 4 * q);
                wof[4*q] = vw.x * so0; wof[4*q+1] = vw.y * so0;
                wof[4*q+2] = vw.z * so0; wof[4*q+3] = vw.w * so0;
            }
        }
        const float* zb = noise + (size_t)b * T_ * H_ + j0;
        const float* xb = input + (size_t)b * T_ * 3;    // wave-uniform
        float* trajBase = out + (size_t)B_ * T_ + (size_t)b * (T_ + 1) * H_;

        {   // trajectories[:,0,:] = h0 (rewritten by emit of phase 0, identical value)
            vfloat4 a = *(const vfloat4*)(h0 + j0);
            vfloat4 c = *(const vfloat4*)(h0 + j0 + 4);
            *(vfloat4*)(trajBase + j0)     = a;
            *(vfloat4*)(trajBase + j0 + 4) = c;
        }

        // Emit half `hh` (8 steps) of finished phase pp: os dot via exact tanh + traj row t.
        auto emit_half = [&](int pp, int hh) {
            const int hf = pp & 1;
            #pragma unroll
            for (int s8 = 0; s8 < 8; ++s8) {
                const int s = hh * 8 + s8;
                const int t = pp * PH + s;
                vfloat4 hl = hb[hf][s][0][lane];
                vfloat4 hh4 = hb[hf][s][1][lane];
                float r0 = fast_tanh(hl.x), r1 = fast_tanh(hl.y);
                float r2 = fast_tanh(hl.z), r3 = fast_tanh(hl.w);
                float r4 = fast_tanh(hh4.x), r5 = fast_tanh(hh4.y);
                float r6 = fast_tanh(hh4.z), r7 = fast_tanh(hh4.w);
                float p2 = r0 * wof[0];
                p2 = __builtin_fmaf(r1, wof[1], p2);
                p2 = __builtin_fmaf(r2, wof[2], p2);
                p2 = __builtin_fmaf(r3, wof[3], p2);
                p2 = __builtin_fmaf(r4, wof[4], p2);
                p2 = __builtin_fmaf(r5, wof[5], p2);
                p2 = __builtin_fmaf(r6, wof[6], p2);
                p2 = __builtin_fmaf(r7, wof[7], p2);
                p2 = wave_reduce1(p2);
                if (lane == 63) os[t] = p2;      // out[t-1] = tanh(h_t)·wo
                float* tr = trajBase + (size_t)t * H_ + j0;
                *(vfloat4*)tr       = hl;
                *(vfloat4*)(tr + 4) = hh4;
            }
        };

        // u for 8 steps starting at global step t0, ring half `half`, slots s0..s0+7.
        auto make_u8 = [&](int t0, int half, int s0, vfloat4* zl, vfloat4* zh) {
            #pragma unroll
            for (int k8 = 0; k8 < 8; ++k8) {
                const int t = t0 + k8;
                float x0 = xb[3*t], x1 = xb[3*t+1], x2 = xb[3*t+2];
                float zz[8] = {zl[k8].x, zl[k8].y, zl[k8].z, zl[k8].w,
                               zh[k8].x, zh[k8].y, zh[k8].z, zh[k8].w};
                float u[8];
                #pragma unroll
                for (int k = 0; k < 8; ++k) {
                    float xw = __builtin_fmaf(x0, wS0[k],
                               __builtin_fmaf(x1, wS1[k], x2 * wS2[k]));
                    u[k] = __builtin_fmaf(zz[k], 0.05f, xw);
                }
                vfloat4 ulo = {u[0], u[1], u[2], u[3]};
                vfloat4 uhi = {u[4], u[5], u[6], u[7]};
                ub[half][s0 + k8][0][lane] = ulo;
                ub[half][s0 + k8][1][lane] = uhi;
            }
        };

        for (int q = 0; q < NFULL; ++q) {
            if (q >= 2) {                        // ring half free + hb(q-2) final
                while (*vcons < q - 1) {}
                asm volatile("" ::: "memory");
            }
            const int half = q & 1;
            // First half: issue z loads, cover with emit, compute u.
            vfloat4 zl[8], zh[8];
            #pragma unroll
            for (int s = 0; s < 8; ++s) {
                const float* g = zb + (size_t)(q * PH + s) * H_;
                zl[s] = *(const vfloat4*)g;
                zh[s] = *(const vfloat4*)(g + 4);
            }
            if (q >= 2) emit_half(q - 2, 0);
            make_u8(q * PH, half, 0, zl, zh);
            // Second half.
            #pragma unroll
            for (int s = 0; s < 8; ++s) {
                const float* g = zb + (size_t)(q * PH + 8 + s) * H_;
                zl[s] = *(const vfloat4*)g;
                zh[s] = *(const vfloat4*)(g + 4);
            }
            if (q >= 2) emit_half(q - 2, 1);
            make_u8(q * PH + 8, half, 8, zl, zh);
            asm volatile("s_waitcnt lgkmcnt(0)" ::: "memory");
            if (lane == 0) *vprod = q + 1;
        }
        // Tail: u for phase 62 (8 steps), emit phases 60, 61, 62, final element.
        {
            while (*vcons < NFULL - 1) {}        // = 61: half 0 free, hb(60) final
            asm volatile("" ::: "memory");
            vfloat4 zl[8], zh[8];
            #pragma unroll
            for (int s = 0; s < 8; ++s) {
                const float* g = zb + (size_t)(NFULL * PH + s) * H_;   // rows 992..999
                zl[s] = *(const vfloat4*)g;
                zh[s] = *(const vfloat4*)(g + 4);
            }
            emit_half(NFULL - 2, 0); emit_half(NFULL - 2, 1);          // phase 60
            make_u8(NFULL * PH, 0, 0, zl, zh);                          // half 62&1 = 0
            asm volatile("s_waitcnt lgkmcnt(0)" ::: "memory");
            if (lane == 0) *vprod = NFULL + 1;                          // 63
            while (*vcons < NFULL) {}            // = 62: hb(61) final
            asm volatile("" ::: "memory");
            emit_half(NFULL - 1, 0); emit_half(NFULL - 1, 1);          // phase 61
            while (*vcons < NFULL + 1) {}        // = 63: hb(62) final
            asm volatile("" ::: "memory");
            emit_half(NFULL, 0);                                        // phase 62 (8 steps)
            while (*vcons < NFULL + 2) {}        // = 64: hfin ready
            asm volatile("" ::: "memory");
            {
                vfloat4 hl = hfin[0][lane], hh4 = hfin[1][lane];
                float p2 = fast_tanh(hl.x) * wof[0];
                p2 = __builtin_fmaf(fast_tanh(hl.y), wof[1], p2);
                p2 = __builtin_fmaf(fast_tanh(hl.z), wof[2], p2);
                p2 = __builtin_fmaf(fast_tanh(hl.w), wof[3], p2);
                p2 = __builtin_fmaf(fast_tanh(hh4.x), wof[4], p2);
                p2 = __builtin_fmaf(fast_tanh(hh4.y), wof[5], p2);
                p2 = __builtin_fmaf(fast_tanh(hh4.z), wof[6], p2);
                p2 = __builtin_fmaf(fast_tanh(hh4.w), wof[7], p2);
                p2 = wave_reduce1(p2);
                if (lane == 63) os[T_] = p2;
                float* tr = trajBase + (size_t)T_ * H_ + j0;   // row 1000 = h_T
                *(vfloat4*)tr       = hl;
                *(vfloat4*)(tr + 4) = hh4;
            }
            asm volatile("s_waitcnt lgkmcnt(0)" ::: "memory");
            float* outp = out + (size_t)b * T_;
            for (int idx = lane; idx < T_; idx += 64)
                outp[idx] = os[idx + 1];
        }
    } else {
        // ========== CONSUMER: Taylor-in-delta chain (R14 body, ships h only) ==========
        vfloat2 n02[4], n12[4], m02[4], m12[4];
        vfloat2 bP[2][4], Tc[2][4], Dc[2][4];
        {
            const float* nb = n + 2 * j0;
            const float* mb = m + 2 * j0;
            #pragma unroll
            for (int q = 0; q < 4; ++q) {
                vfloat4 vn = *(const vfloat4*)(nb + 4 * q);
                vfloat2 a = {vn.x, vn.z}; n02[q] = a;
                vfloat2 c = {vn.y, vn.w}; n12[q] = c;
                vfloat4 vm = *(const vfloat4*)(mb + 4 * q);
                vfloat2 d = {0.2f * vm.x, 0.2f * vm.z}; m02[q] = d;
                vfloat2 e = {0.2f * vm.y, 0.2f * vm.w}; m12[q] = e;
            }
            #pragma unroll
            for (int q = 0; q < 2; ++q) {
                vfloat4 vh = *(const vfloat4*)(h0 + j0 + 4 * q);
                vfloat2 lo = {vh.x, vh.y}, hi = {vh.z, vh.w};
                bP[0][2*q] = lo; bP[0][2*q+1] = hi;
            }
            #pragma unroll
            for (int j = 0; j < 4; ++j) {
                vfloat2 T = {fast_tanh(bP[0][j].x), fast_tanh(bP[0][j].y)};
                Tc[0][j] = T;
                Dc[0][j] = 1.0f - T * T;
            }
        }
        float a0s = 0.0f, a1s = 0.0f;

        // One step (pp/np compile-time via unroll).
        auto STEP = [&](int half, int s, int L) {
            const int pp = s & 1;
            const int np = pp ^ 1;
            vfloat4 cul = ub[half][s][0][lane];
            vfloat4 cuh = ub[half][s][1][lane];
            vfloat2 a02 = bc2(a0s), a12 = bc2(a1s);

            // ---- ON-CHAIN: delta -> r(Taylor) -> dot -> reduce ----
            vfloat2 dl[4], r2[4], h2[4];
            #pragma unroll
            for (int j = 0; j < 4; ++j)
                dl[j] = a02 * m02[j] + a12 * m12[j];
            #pragma unroll
            for (int j = 0; j < 4; ++j) {
                vfloat2 t1 = Tc[pp][j] * dl[j];
                vfloat2 e  = dl[j] - t1 * dl[j];
                r2[j] = Dc[pp][j] * e + Tc[pp][j];
            }
            vfloat2 A0 = r2[1] * n02[1] + r2[0] * n02[0];
            vfloat2 B0 = r2[3] * n02[3] + r2[2] * n02[2];
            vfloat2 P0 = A0 + B0;
            float p0 = P0.x + P0.y;
            vfloat2 A1 = r2[1] * n12[1] + r2[0] * n12[0];
            vfloat2 B1 = r2[3] * n12[3] + r2[2] * n12[2];
            vfloat2 P1 = A1 + B1;
            float p1 = P1.x + P1.y;
            wave_reduce2(p0, p1);

            // ---- OFF-CHAIN ----
            vfloat2 u2[4];
            vfloat2 t0 = {cul.x, cul.y}; u2[0] = t0;
            vfloat2 t1v = {cul.z, cul.w}; u2[1] = t1v;
            vfloat2 t2 = {cuh.x, cuh.y}; u2[2] = t2;
            vfloat2 t3 = {cuh.z, cuh.w}; u2[3] = t3;
            #pragma unroll
            for (int j = 0; j < 4; ++j) {
                h2[j] = bP[pp][j] + dl[j];                   // h_t exact
                bP[np][j] = h2[j] * 0.8f + u2[j];            // base_t
            }
            #pragma unroll
            for (int j = 0; j < 4; ++j) {
                vfloat2 x2 = bP[np][j] * C2_;
                vfloat2 E  = {__builtin_amdgcn_exp2f(x2.x),
                              __builtin_amdgcn_exp2f(x2.y)};
                vfloat2 DD = E + 1.0f;
                vfloat2 R  = {__builtin_amdgcn_rcpf(DD.x),
                              __builtin_amdgcn_rcpf(DD.y)};
                vfloat2 T  = bc2(-2.0f) * R + 1.0f;
                Tc[np][j] = T;
                Dc[np][j] = 1.0f - T * T;
            }

            // Ship h_t only.
            vfloat4 hlo = {h2[0].x, h2[0].y, h2[1].x, h2[1].y};
            vfloat4 hhi = {h2[2].x, h2[2].y, h2[3].x, h2[3].y};
            hb[half][s][0][lane] = hlo;
            hb[half][s][1][lane] = hhi;

            a0s = __int_as_float(__builtin_amdgcn_readlane(__float_as_int(p0), 63));
            a1s = __int_as_float(__builtin_amdgcn_readlane(__float_as_int(p1), 63));
        };

        for (int p = 0; p < NFULL; ++p) {
            while (*vprod < p + 1) {}
            asm volatile("" ::: "memory");
            const int half = p & 1;
            #pragma unroll
            for (int s = 0; s < PH; ++s) STEP(half, s, PH);
            asm volatile("s_waitcnt lgkmcnt(0)" ::: "memory");
            if (lane == 0) *vcons = p + 1;
        }
        // Tail phase 62 (8 steps, half 0).
        {
            while (*vprod < NFULL + 1) {}
            asm volatile("" ::: "memory");
            #pragma unroll
            for (int s = 0; s < 8; ++s) STEP(0, s, 8);
            asm volatile("s_waitcnt lgkmcnt(0)" ::: "memory");
            if (lane == 0) *vcons = NFULL + 1;       // 63
        }
        // Final: h_T = base_999 + delta_999 (parity 0 after 1000 steps).
        {
            vfloat2 a02 = bc2(a0s), a12 = bc2(a1s);
            float hT8[8];
            #pragma unroll
            for (int j = 0; j < 4; ++j) {
                vfloat2 dlt = a02 * m02[j] + a12 * m12[j];
                vfloat2 hT  = bP[0][j] + dlt;
                hT8[2*j] = hT.x; hT8[2*j+1] = hT.y;
            }
            vfloat4 hlo = {hT8[0], hT8[1], hT8[2], hT8[3]};
            vfloat4 hhi = {hT8[4], hT8[5], hT8[6], hT8[7]};
            hfin[0][lane] = hlo;
            hfin[1][lane] = hhi;
            asm volatile("s_waitcnt lgkmcnt(0)" ::: "memory");
            if (lane == 0) *vcons = NFULL + 2;       // 64
        }
    }
}

extern "C" void kernel_launch(void* const* d_in, const int* in_sizes, int n_in,
                              void* d_out, int out_size, void* d_ws, size_t ws_size,
                              hipStream_t stream) {
    const float* input = (const float*)d_in[0];
    const float* noise = (const float*)d_in[1];
    const float* wi    = (const float*)d_in[2];
    const float* si    = (const float*)d_in[3];
    const float* m     = (const float*)d_in[4];
    const float* n     = (const float*)d_in[5];
    const float* wo    = (const float*)d_in[6];
    const float* so    = (const float*)d_in[7];
    const float* h0    = (const float*)d_in[8];
    float* out = (float*)d_out;

    hipLaunchKernelGGL(lowrank_rnn_kernel, dim3(B_), dim3(128), 0, stream,
                       input, noise, wi, si, m, n, wo, so, h0, out);
}